// Round 1
// baseline (1094.287 us; speedup 1.0000x reference)
//
#include <hip/hip_runtime.h>
#include <math.h>

#define D_ 256
#define NS_ 64
#define KNB_ 8
#define SEQ_ 1024
#define B_ 4
#define NEG_ (-10000.0f)

__device__ __forceinline__ float waveSum(float v) {
#pragma unroll
    for (int off = 32; off; off >>= 1) v += __shfl_xor(v, off, 64);
    return v;
}

// block-wide sum, result broadcast to all 256 threads
__device__ __forceinline__ float blockSum(float v, float* scr) {
    const int tid = threadIdx.x;
    const int wid = tid >> 6, lane = tid & 63;
    v = waveSum(v);
    __syncthreads();               // protect scr from previous use
    if (lane == 0) scr[wid] = v;
    __syncthreads();
    return scr[0] + scr[1] + scr[2] + scr[3];
}

// sparsemax threshold: solves sum(max(z - tau, 0)) == 1, tau in [max-1, max]
__device__ float sparsemaxTau(const float* z, float* scr) {
    const int tid = threadIdx.x;
    const int wid = tid >> 6, lane = tid & 63;
    const float a0 = z[tid], a1 = z[tid + 256], a2 = z[tid + 512], a3 = z[tid + 768];
    float mx = fmaxf(fmaxf(a0, a1), fmaxf(a2, a3));
#pragma unroll
    for (int off = 32; off; off >>= 1) mx = fmaxf(mx, __shfl_xor(mx, off, 64));
    __syncthreads();
    if (lane == 0) scr[wid] = mx;
    __syncthreads();
    mx = fmaxf(fmaxf(scr[0], scr[1]), fmaxf(scr[2], scr[3]));
    float lo = mx - 1.0f, hi = mx;
    for (int it = 0; it < 30; ++it) {
        const float mid = 0.5f * (lo + hi);
        float p = fmaxf(a0 - mid, 0.f) + fmaxf(a1 - mid, 0.f) +
                  fmaxf(a2 - mid, 0.f) + fmaxf(a3 - mid, 0.f);
        const float tot = blockSum(p, scr);
        if (tot > 1.0f) lo = mid; else hi = mid;   // uniform branch (tot broadcast)
    }
    return 0.5f * (lo + hi);
}

// classify mask buffer dtype: 0 = int32 0/1, 1 = uint8, 2 = float32 0/1
__global__ void detect_mask_kernel(const unsigned int* __restrict__ mw, int* __restrict__ flag) {
    __shared__ int notI, notF;
    if (threadIdx.x == 0) { notI = 0; notF = 0; }
    __syncthreads();
    int ni = 0, nf = 0;
    for (int i = threadIdx.x; i < 1024; i += 256) {
        const unsigned int w = mw[i];
        if (w != 0u && w != 1u) ni = 1;
        if (w != 0u && w != 0x3f800000u) nf = 1;
    }
    if (ni) atomicOr(&notI, 1);
    if (nf) atomicOr(&notF, 1);
    __syncthreads();
    if (threadIdx.x == 0) *flag = (!notI) ? 0 : ((!notF) ? 2 : 1);
}

__global__ __launch_bounds__(256) void precompute_kernel(
    const float* __restrict__ hidden,
    const float* __restrict__ scn,
    const float* __restrict__ gvel,
    const float* __restrict__ ctx,
    const float* __restrict__ ent,
    const float* __restrict__ W_vel,
    const float* __restrict__ W_probe,
    const float* __restrict__ W_gate,
    const float* __restrict__ b_gate,
    float* __restrict__ wsEnd,
    float* __restrict__ wsHa,
    float* __restrict__ wsProbe,
    int* __restrict__ wsMode,
    float* __restrict__ wsHn,
    float* __restrict__ wsGw)
{
    __shared__ float hid[D_];
    __shared__ float gvl[NS_];
    __shared__ float scl[NS_];
    __shared__ float scr[4];
    const int row = blockIdx.x;       // b*SEQ + s
    const int tid = threadIdx.x;

    hid[tid] = hidden[(size_t)row * D_ + tid];
    if (tid < NS_) { gvl[tid] = gvel[(size_t)row * NS_ + tid]; scl[tid] = scn[(size_t)row * NS_ + tid]; }
    __syncthreads();

    if (tid < 64) {   // wave 0: endpoint normalize + argmax mode
        const float e = scl[tid] + 0.4f * gvl[tid];
        const float ss = waveSum(e * e);
        wsEnd[(size_t)row * NS_ + tid] = e / fmaxf(sqrtf(ss), 1e-12f);
        float v = scl[tid]; int idx = tid;
#pragma unroll
        for (int off = 1; off < 64; off <<= 1) {
            const float ov = __shfl_xor(v, off, 64);
            const int   oi = __shfl_xor(idx, off, 64);
            if (ov > v || (ov == v && oi < idx)) { v = ov; idx = oi; }  // first-index tie-break
        }
        if (tid == 0) wsMode[row] = idx;
    }

    // vel_h = gv @ W_vel.T ; h_aimed = normalize(hidden + 0.3*vel_h)
    float vh = 0.f;
    const float4* wv4 = (const float4*)(W_vel + (size_t)tid * NS_);
#pragma unroll
    for (int e = 0; e < NS_ / 4; ++e) {
        const float4 w = wv4[e];
        vh += gvl[e * 4] * w.x + gvl[e * 4 + 1] * w.y + gvl[e * 4 + 2] * w.z + gvl[e * 4 + 3] * w.w;
    }
    const float ha = hid[tid] + 0.3f * vh;
    const float ssA = blockSum(ha * ha, scr);
    wsHa[(size_t)row * D_ + tid] = ha / fmaxf(sqrtf(ssA), 1e-12f);

    // probe = normalize(hidden @ W_probe.T)
    float pr = 0.f;
    const float4* wp4 = (const float4*)(W_probe + (size_t)tid * D_);
    for (int e = 0; e < D_ / 4; ++e) {
        const float4 w = wp4[e];
        pr += hid[e * 4] * w.x + hid[e * 4 + 1] * w.y + hid[e * 4 + 2] * w.z + hid[e * 4 + 3] * w.w;
    }
    const float ssP = blockSum(pr * pr, scr);
    wsProbe[(size_t)row * D_ + tid] = pr / fmaxf(sqrtf(ssP), 1e-12f);

    // gate: sigmoid(hidden . W_gate + b_gate) * ctx_conf ; entropy norm
    const float gd = blockSum(hid[tid] * W_gate[tid], scr);
    if (tid == 0) {
        const float raw = 1.f / (1.f + expf(-(gd + b_gate[0])));
        wsGw[row] = raw * ctx[row];
        wsHn[row] = ent[row] / 10.37349119f;   // log(32000)+1e-8
    }
}

__global__ __launch_bounds__(256) void row_kernel(
    const float* __restrict__ messages,
    const float* __restrict__ scn,
    const int* __restrict__ x_ids,
    const void* __restrict__ maskP,
    const int* __restrict__ static_nb,
    const float* __restrict__ W_e1,
    const float* __restrict__ b_e1,
    const float* __restrict__ W_e2,
    const float* __restrict__ b_e2,
    const float* __restrict__ wsEnd,
    const float* __restrict__ wsHa,
    const float* __restrict__ wsProbe,
    const int* __restrict__ wsMode,
    const float* __restrict__ wsHn,
    const float* __restrict__ wsGw,
    const int* __restrict__ maskFlag,
    float* __restrict__ out)
{
    __shared__ __align__(16) float sh_h[D_];
    __shared__ float sh_e[NS_];
    __shared__ float sh_s[NS_];
    __shared__ float zg[SEQ_];
    __shared__ float zl[SEQ_];
    __shared__ float msum[KNB_][D_];
    __shared__ float ssum[KNB_][NS_];
    __shared__ float edgeb[KNB_];
    __shared__ float cntk[KNB_];
    __shared__ int   nbv[KNB_];
    __shared__ int   mlp[128];
    __shared__ int   mlk[128];
    __shared__ int   tlist[SEQ_];
    __shared__ int   counters[4];   // 0: match count, 1: hasNb, 2: geo support, 3: local support
    __shared__ float scr[4];
    __shared__ float covSh;

    const int row = blockIdx.x;
    const int b = row >> 10;
    const int s = row & 1023;
    const int tid = threadIdx.x;
    const int wid = tid >> 6, lane = tid & 63;

    const float* msgB = messages + (size_t)b * SEQ_ * D_;
    const float* scnB = scn + (size_t)b * SEQ_ * NS_;

    sh_h[tid] = wsHa[(size_t)row * D_ + tid];
    if (tid < NS_) { sh_e[tid] = wsEnd[(size_t)row * NS_ + tid]; sh_s[tid] = scnB[(size_t)s * NS_ + tid]; }
    for (int i = tid; i < KNB_ * D_; i += 256) (&msum[0][0])[i] = 0.f;
    for (int i = tid; i < KNB_ * NS_; i += 256) (&ssum[0][0])[i] = 0.f;
    if (tid < KNB_) { cntk[tid] = 0.f; nbv[tid] = static_nb[(size_t)x_ids[row] * KNB_ + tid]; }
    if (tid < 4) counters[tid] = 0;
    __syncthreads();

    const int mf = *maskFlag;
    const unsigned char* m8 = (const unsigned char*)maskP;
    const int* m32 = (const int*)maskP;
    const float* mfl = (const float*)maskP;
    const int modeS = wsMode[row];
    const float Hn = wsHn[row];

    // ---- sweep over t: wave w handles t in [w*256, w*256+256) ----
    int sameAny = 0;
    const int t0 = wid << 8;
    for (int tt = 0; tt < 256; ++tt) {
        const int t = t0 + tt;
        const float4 m4 = *(const float4*)(msgB + (size_t)t * D_ + (lane << 2));
        const float4 h4 = *(const float4*)(sh_h + (lane << 2));
        float ph = m4.x * h4.x + m4.y * h4.y + m4.z * h4.z + m4.w * h4.w;
        const float st = scnB[(size_t)t * NS_ + lane];
        float pe = sh_e[lane] * st;
        float ps = sh_s[lane] * st;
#pragma unroll
        for (int off = 32; off; off >>= 1) {
            ph += __shfl_xor(ph, off, 64);
            pe += __shfl_xor(pe, off, 64);
            ps += __shfl_xor(ps, off, 64);
        }
        const size_t midx = (size_t)s * SEQ_ + t;
        const bool blk = (t == s) ||
            (mf == 1 ? (m8[midx] != 0) : (mf == 2 ? (mfl[midx] != 0.f) : (m32[midx] != 0)));
        const bool same = (!blk) && (wsMode[(b << 10) + t] == modeS);
        if (lane == 0) {
            zg[t] = blk ? NEG_ : (pe * Hn + 0.5f * ph) * 5.0f;
            zl[t] = same ? ps : 0.0f;   // raw scn_sim, finalized below
        }
        if (same) sameAny = 1;
    }
    if (lane == 0 && sameAny) atomicOr(&counters[1], 1);
    __syncthreads();
    const bool hasNb = counters[1] != 0;

    // ---- finalize local routing scores ----
    for (int t = tid; t < SEQ_; t += 256) {
        const size_t midx = (size_t)s * SEQ_ + t;
        const bool blk = (t == s) ||
            (mf == 1 ? (m8[midx] != 0) : (mf == 2 ? (mfl[midx] != 0.f) : (m32[midx] != 0)));
        float z;
        if (blk) z = NEG_ * 5.0f;
        else if (hasNb) z = zl[t] * 5.0f;
        else z = -0.05f * fabsf((float)(s - t));
        zl[t] = z;
    }

    // ---- static neighbor-vocab scan (matches are rare) ----
    for (int p = tid; p <= s; p += 256) {
        const int id = x_ids[(b << 10) + p];
#pragma unroll
        for (int k = 0; k < KNB_; ++k) {
            if (id == nbv[k]) {
                atomicAdd(&cntk[k], 1.0f);
                const int i = atomicAdd(&counters[0], 1);
                if (i < 128) { mlp[i] = p; mlk[i] = k; }
            }
        }
    }
    __syncthreads();
    const int nm = min(counters[0], 128);
    for (int i = 0; i < nm; ++i) {
        const int p = mlp[i], k = mlk[i];
        msum[k][tid] += msgB[(size_t)p * D_ + tid];
        if (tid < NS_) ssum[k][tid] += scnB[(size_t)p * NS_ + tid];
    }
    __syncthreads();

    // ---- geo sparsemax + sparse aggregation ----
    const float tauG = sparsemaxTau(zg, scr);
    for (int t = tid; t < SEQ_; t += 256)
        if (zg[t] > tauG) { const int i = atomicAdd(&counters[2], 1); tlist[i] = t; }
    __syncthreads();
    const int ng = counters[2];
    float aggG = 0.f;
    for (int i = 0; i < ng; ++i) {
        const int t = tlist[i];
        aggG += (zg[t] - tauG) * msgB[(size_t)t * D_ + tid];
    }

    // ---- local sparsemax + sparse aggregation (barriers inside tau protect tlist) ----
    const float tauL = sparsemaxTau(zl, scr);
    for (int t = tid; t < SEQ_; t += 256)
        if (zl[t] > tauL) { const int i = atomicAdd(&counters[3], 1); tlist[i] = t; }
    __syncthreads();
    const int nl = counters[3];
    float aggL = 0.f;
    for (int i = 0; i < nl; ++i) {
        const int t = tlist[i];
        aggL += (zl[t] - tauL) * msgB[(size_t)t * D_ + tid];
    }
    __syncthreads();

    // ---- static edge MLP (gelu exact) + softmax over 8 ----
    for (int k = wid; k < KNB_; k += 4) {
        float pv = ssum[k][lane] * sh_s[lane];
#pragma unroll
        for (int off = 32; off; off >>= 1) pv += __shfl_xor(pv, off, 64);
        if (lane == 0) {
            float eo = 0.f;
#pragma unroll
            for (int j = 0; j < KNB_; ++j) {
                const float x = pv * W_e1[j] + b_e1[j];
                const float g = 0.5f * x * (1.0f + erff(x * 0.70710678118654752f));
                eo += g * W_e2[j];
            }
            edgeb[k] = eo + b_e2[0];
        }
    }
    __syncthreads();
    if (tid == 0) {
        float mx = edgeb[0];
        for (int k = 1; k < KNB_; ++k) mx = fmaxf(mx, edgeb[k]);
        float smv = 0.f, ex[KNB_];
        for (int k = 0; k < KNB_; ++k) { ex[k] = expf(edgeb[k] - mx); smv += ex[k]; }
        for (int k = 0; k < KNB_; ++k) edgeb[k] = ex[k] / smv;
        float cov = 0.f;
        for (int k = 0; k < KNB_; ++k) cov += fminf(cntk[k], 1.0f);
        covSh = cov * 0.125f;
    }
    __syncthreads();
    float aggS = 0.f;
#pragma unroll
    for (int k = 0; k < KNB_; ++k) aggS += msum[k][tid] * edgeb[k];

    // ---- gated fusion epilogue ----
    const float cov = covSh;
    const float gw = wsGw[row];
    const float sfin = cov * aggS + (1.f - cov) * aggL;
    const float agg = gw * aggG + (1.f - gw) * sfin;
    const float ssq = blockSum(agg * agg, scr);
    const float nrm = fmaxf(sqrtf(ssq), 1e-12f);
    const float dp = blockSum((agg / nrm) * wsProbe[(size_t)row * D_ + tid], scr);
    const float rel = 1.f / (1.f + expf(-dp));
    out[(size_t)row * D_ + tid] = agg * rel;
}

extern "C" void kernel_launch(void* const* d_in, const int* in_sizes, int n_in,
                              void* d_out, int out_size, void* d_ws, size_t ws_size,
                              hipStream_t stream) {
    const float* messages  = (const float*)d_in[0];
    const float* hidden    = (const float*)d_in[1];
    const int*   x_ids     = (const int*)d_in[2];
    const float* scn       = (const float*)d_in[3];
    const void*  mask      = d_in[4];
    const int*   static_nb = (const int*)d_in[5];
    const float* gvel      = (const float*)d_in[6];
    const float* ctx       = (const float*)d_in[7];
    const float* ent       = (const float*)d_in[8];
    const float* W_vel     = (const float*)d_in[9];
    const float* W_e1      = (const float*)d_in[10];
    const float* b_e1      = (const float*)d_in[11];
    const float* W_e2      = (const float*)d_in[12];
    const float* b_e2      = (const float*)d_in[13];
    const float* W_probe   = (const float*)d_in[14];
    const float* W_gate    = (const float*)d_in[15];
    const float* b_gate    = (const float*)d_in[16];
    float* out = (float*)d_out;
    (void)in_sizes; (void)n_in; (void)out_size; (void)ws_size;

    char* ws = (char*)d_ws;
    size_t o = 0;
    int* flag      = (int*)(ws + o);   o += 256;
    float* wsEnd   = (float*)(ws + o); o += (size_t)B_ * SEQ_ * NS_ * 4;
    float* wsHa    = (float*)(ws + o); o += (size_t)B_ * SEQ_ * D_ * 4;
    float* wsProbe = (float*)(ws + o); o += (size_t)B_ * SEQ_ * D_ * 4;
    int* wsMode    = (int*)(ws + o);   o += (size_t)B_ * SEQ_ * 4;
    float* wsHn    = (float*)(ws + o); o += (size_t)B_ * SEQ_ * 4;
    float* wsGw    = (float*)(ws + o); o += (size_t)B_ * SEQ_ * 4;

    detect_mask_kernel<<<dim3(1), dim3(256), 0, stream>>>((const unsigned int*)mask, flag);
    precompute_kernel<<<dim3(B_ * SEQ_), dim3(256), 0, stream>>>(
        hidden, scn, gvel, ctx, ent, W_vel, W_probe, W_gate, b_gate,
        wsEnd, wsHa, wsProbe, wsMode, wsHn, wsGw);
    row_kernel<<<dim3(B_ * SEQ_), dim3(256), 0, stream>>>(
        messages, scn, x_ids, mask, static_nb, W_e1, b_e1, W_e2, b_e2,
        wsEnd, wsHa, wsProbe, wsMode, wsHn, wsGw, flag, out);
}

// Round 2
// 240.564 us; speedup vs baseline: 4.5488x; 4.5488x over previous
//
#include <hip/hip_runtime.h>
#include <math.h>

#define D_ 256
#define NS_ 64
#define KNB_ 8
#define SEQ_ 1024
#define B_ 4
#define NEG_ (-10000.0f)
#define BLKNEG_ (-50000.0f)

__device__ __forceinline__ float waveSum(float v) {
#pragma unroll
    for (int off = 32; off; off >>= 1) v += __shfl_xor(v, off, 64);
    return v;
}

__device__ __forceinline__ float blockSum(float v, float* scr) {
    const int tid = threadIdx.x;
    const int wid = tid >> 6, lane = tid & 63;
    v = waveSum(v);
    __syncthreads();
    if (lane == 0) scr[wid] = v;
    __syncthreads();
    return scr[0] + scr[1] + scr[2] + scr[3];
}

// classify mask buffer dtype: 0 = int32 0/1, 1 = uint8, 2 = float32 0/1
__global__ void detect_mask_kernel(const unsigned int* __restrict__ mw, int* __restrict__ flag) {
    __shared__ int notI, notF;
    if (threadIdx.x == 0) { notI = 0; notF = 0; }
    __syncthreads();
    int ni = 0, nf = 0;
    for (int i = threadIdx.x; i < 1024; i += 256) {
        const unsigned int w = mw[i];
        if (w != 0u && w != 1u) ni = 1;
        if (w != 0u && w != 0x3f800000u) nf = 1;
    }
    if (ni) atomicOr(&notI, 1);
    if (nf) atomicOr(&notF, 1);
    __syncthreads();
    if (threadIdx.x == 0) *flag = (!notI) ? 0 : ((!notF) ? 2 : 1);
}

// generic [Rr x Cc] -> [Cc x Rr] per-batch transpose; Rr,Cc multiples of 32
__global__ __launch_bounds__(256) void transpose_kernel(
    const float* __restrict__ src, float* __restrict__ dst, int Rr, int Cc)
{
    __shared__ float tile[32][33];
    const int bz = blockIdx.z;
    const int c0 = blockIdx.x << 5, r0 = blockIdx.y << 5;
    const float* s = src + (size_t)bz * Rr * Cc;
    float* d = dst + (size_t)bz * Rr * Cc;
    const int tx = threadIdx.x, ty = threadIdx.y;
#pragma unroll
    for (int i = 0; i < 32; i += 8)
        tile[ty + i][tx] = s[(size_t)(r0 + ty + i) * Cc + c0 + tx];
    __syncthreads();
#pragma unroll
    for (int i = 0; i < 32; i += 8)
        d[(size_t)(c0 + ty + i) * Rr + r0 + tx] = tile[tx][ty + i];
}

__global__ __launch_bounds__(256) void precompute_light(
    const float* __restrict__ hidden,
    const float* __restrict__ scn,
    const float* __restrict__ gvel,
    const float* __restrict__ ctx,
    const float* __restrict__ ent,
    const float* __restrict__ WvT,     // [NS][D]
    const float* __restrict__ W_gate,
    const float* __restrict__ b_gate,
    float* __restrict__ wsEnd,
    float* __restrict__ wsHa,
    int* __restrict__ wsMode,
    float* __restrict__ wsHn,
    float* __restrict__ wsGw)
{
    __shared__ float scr[4];
    const int row = blockIdx.x;
    const int tid = threadIdx.x;

    if (tid < 64) {   // wave0: endpoint normalize + argmax mode
        const float sv = scn[(size_t)row * NS_ + tid];
        const float gv = gvel[(size_t)row * NS_ + tid];
        const float e = sv + 0.4f * gv;
        const float ss = waveSum(e * e);
        wsEnd[(size_t)row * NS_ + tid] = e / fmaxf(sqrtf(ss), 1e-12f);
        float v = sv; int idx = tid;
#pragma unroll
        for (int off = 1; off < 64; off <<= 1) {
            const float ov = __shfl_xor(v, off, 64);
            const int   oi = __shfl_xor(idx, off, 64);
            if (ov > v || (ov == v && oi < idx)) { v = ov; idx = oi; }
        }
        if (tid == 0) wsMode[row] = idx;
    }

    // vel_h[tid] = sum_e gvel_row[e] * WvT[e][tid]   (gvel uniform -> s_load)
    const float* gRow = gvel + (size_t)row * NS_;
    float vh = 0.f;
#pragma unroll
    for (int e = 0; e < NS_; e += 4) {
        const float4 g4 = *(const float4*)(gRow + e);
        vh = fmaf(g4.x, WvT[(size_t)(e + 0) * D_ + tid],
             fmaf(g4.y, WvT[(size_t)(e + 1) * D_ + tid],
             fmaf(g4.z, WvT[(size_t)(e + 2) * D_ + tid],
             fmaf(g4.w, WvT[(size_t)(e + 3) * D_ + tid], vh))));
    }
    const float hd = hidden[(size_t)row * D_ + tid];
    const float ha = hd + 0.3f * vh;
    const float ssA = blockSum(ha * ha, scr);
    wsHa[(size_t)row * D_ + tid] = ha / fmaxf(sqrtf(ssA), 1e-12f);

    const float gd = blockSum(hd * W_gate[tid], scr);
    if (tid == 0) {
        const float raw = 1.f / (1.f + expf(-(gd + b_gate[0])));
        wsGw[row] = raw * ctx[row];
        wsHn[row] = ent[row] / 10.373491191781864f;   // log(32000)+1e-8
    }
}

// probe = normalize(hidden @ W_probe^T), 4 rows per block via transposed W_probe
__global__ __launch_bounds__(256) void probe4_kernel(
    const float* __restrict__ hidden,
    const float* __restrict__ WpT,     // [D][D] = W_probe^T
    float* __restrict__ wsProbe)
{
    __shared__ float scr[4];
    const int rowBase = blockIdx.x << 2;
    const int tid = threadIdx.x;
    const float* h0 = hidden + (size_t)rowBase * D_;
    float acc[4] = {0.f, 0.f, 0.f, 0.f};
    for (int e = 0; e < D_; e += 4) {
        const float w0 = WpT[(size_t)(e + 0) * D_ + tid];
        const float w1 = WpT[(size_t)(e + 1) * D_ + tid];
        const float w2 = WpT[(size_t)(e + 2) * D_ + tid];
        const float w3 = WpT[(size_t)(e + 3) * D_ + tid];
#pragma unroll
        for (int r = 0; r < 4; ++r) {
            const float4 h4 = *(const float4*)(h0 + (size_t)r * D_ + e);  // uniform
            acc[r] = fmaf(h4.x, w0, fmaf(h4.y, w1, fmaf(h4.z, w2, fmaf(h4.w, w3, acc[r]))));
        }
    }
#pragma unroll
    for (int r = 0; r < 4; ++r) {
        const float ssq = blockSum(acc[r] * acc[r], scr);
        wsProbe[(size_t)(rowBase + r) * D_ + tid] = acc[r] / fmaxf(sqrtf(ssq), 1e-12f);
    }
}

__global__ __launch_bounds__(256) void row4_kernel(
    const float* __restrict__ messages,
    const float* __restrict__ msgT,     // [B][D][S]
    const float* __restrict__ scnT,     // [B][NS][S]
    const float* __restrict__ scn,
    const int* __restrict__ x_ids,
    const void* __restrict__ maskP,
    const int* __restrict__ static_nb,
    const float* __restrict__ W_e1,
    const float* __restrict__ b_e1,
    const float* __restrict__ W_e2,
    const float* __restrict__ b_e2,
    const float* __restrict__ wsEnd,
    const float* __restrict__ wsHa,
    const float* __restrict__ wsProbe,
    const int* __restrict__ wsMode,
    const float* __restrict__ wsHn,
    const float* __restrict__ wsGw,
    const int* __restrict__ maskFlag,
    float* __restrict__ out)
{
    __shared__ float zg[4][SEQ_];
    __shared__ float zl[4][SEQ_];
    __shared__ int   mlist[4][64];
    __shared__ int   hasNbSh[4];

    // XCD-aware swizzle: XCD pair {2b,2b+1} handles batch b (L2 working set fits)
    const int bid = blockIdx.x;
    const int xcd = bid & 7, jj0 = bid >> 3;
    const int b = xcd >> 1;
    const int sBase = (((xcd & 1) << 7) + jj0) << 2;   // 4 rows per block
    const int rowBase = (b << 10) + sBase;

    const int tid = threadIdx.x;
    const int wid = tid >> 6, lane = tid & 63;

    if (tid < 4) hasNbSh[tid] = 0;
    __syncthreads();

    // ---------- phase 1: z = sims via register-tiled GEMM over transposed operands ----------
    const float* msgTb = msgT + (size_t)b * D_ * SEQ_;
    const float* scnTb = scnT + (size_t)b * NS_ * SEQ_;
    const float* hA = wsHa + (size_t)rowBase * D_;     // 4 rows, wave-uniform reads
    const float* eA = wsEnd + (size_t)rowBase * NS_;
    const float* sA = scn + (size_t)rowBase * NS_;
    const int tcol = tid << 2;                         // this thread's 4 t's

    float zh[4][4] = {}; float ze[4][4] = {}; float zs[4][4] = {};
    for (int dc = 0; dc < D_; dc += 4) {
        float4 mv[4];
#pragma unroll
        for (int dj = 0; dj < 4; ++dj)
            mv[dj] = *(const float4*)(msgTb + (size_t)(dc + dj) * SEQ_ + tcol);
#pragma unroll
        for (int r = 0; r < 4; ++r) {
            const float4 h4 = *(const float4*)(hA + (size_t)r * D_ + dc);   // uniform
            const float hx[4] = {h4.x, h4.y, h4.z, h4.w};
#pragma unroll
            for (int dj = 0; dj < 4; ++dj) {
                zh[r][0] = fmaf(hx[dj], mv[dj].x, zh[r][0]);
                zh[r][1] = fmaf(hx[dj], mv[dj].y, zh[r][1]);
                zh[r][2] = fmaf(hx[dj], mv[dj].z, zh[r][2]);
                zh[r][3] = fmaf(hx[dj], mv[dj].w, zh[r][3]);
            }
        }
    }
    for (int dc = 0; dc < NS_; dc += 4) {
        float4 sv[4];
#pragma unroll
        for (int dj = 0; dj < 4; ++dj)
            sv[dj] = *(const float4*)(scnTb + (size_t)(dc + dj) * SEQ_ + tcol);
#pragma unroll
        for (int r = 0; r < 4; ++r) {
            const float4 e4 = *(const float4*)(eA + (size_t)r * NS_ + dc);  // uniform
            const float4 s4 = *(const float4*)(sA + (size_t)r * NS_ + dc);  // uniform
            const float ex[4] = {e4.x, e4.y, e4.z, e4.w};
            const float sx[4] = {s4.x, s4.y, s4.z, s4.w};
#pragma unroll
            for (int dj = 0; dj < 4; ++dj) {
                ze[r][0] = fmaf(ex[dj], sv[dj].x, ze[r][0]);
                ze[r][1] = fmaf(ex[dj], sv[dj].y, ze[r][1]);
                ze[r][2] = fmaf(ex[dj], sv[dj].z, ze[r][2]);
                ze[r][3] = fmaf(ex[dj], sv[dj].w, ze[r][3]);
                zs[r][0] = fmaf(sx[dj], sv[dj].x, zs[r][0]);
                zs[r][1] = fmaf(sx[dj], sv[dj].y, zs[r][1]);
                zs[r][2] = fmaf(sx[dj], sv[dj].z, zs[r][2]);
                zs[r][3] = fmaf(sx[dj], sv[dj].w, zs[r][3]);
            }
        }
    }

    // ---------- z-write: mask + mode, store to LDS ----------
    const int mf = *maskFlag;
    const int4 md = *(const int4*)(wsMode + (b << 10) + tcol);
    const int mdx[4] = {md.x, md.y, md.z, md.w};
#pragma unroll
    for (int r = 0; r < 4; ++r) {
        const int s_r = sBase + r;
        const float Hn = wsHn[rowBase + r];
        const int mS = wsMode[rowBase + r];
        int blk[4];
        const size_t mb = (size_t)s_r * SEQ_ + tcol;
        if (mf == 1) {
            const uchar4 m = *(const uchar4*)((const unsigned char*)maskP + mb);
            blk[0] = m.x != 0; blk[1] = m.y != 0; blk[2] = m.z != 0; blk[3] = m.w != 0;
        } else if (mf == 2) {
            const float4 m = *(const float4*)((const float*)maskP + mb);
            blk[0] = m.x != 0.f; blk[1] = m.y != 0.f; blk[2] = m.z != 0.f; blk[3] = m.w != 0.f;
        } else {
            const int4 m = *(const int4*)((const int*)maskP + mb);
            blk[0] = m.x != 0; blk[1] = m.y != 0; blk[2] = m.z != 0; blk[3] = m.w != 0;
        }
        const int dlt = s_r - tcol;
        if ((unsigned)dlt < 4u) blk[dlt] = 1;
        float zgv[4], zlv[4];
        int any = 0;
#pragma unroll
        for (int j = 0; j < 4; ++j) {
            zgv[j] = blk[j] ? NEG_ : (ze[r][j] * Hn + 0.5f * zh[r][j]) * 5.0f;
            const int sm = (!blk[j]) && (mdx[j] == mS);
            any |= sm;
            zlv[j] = sm ? zs[r][j] * 5.0f : (blk[j] ? BLKNEG_ : 0.0f);
        }
        *(float4*)(&zg[r][tcol]) = make_float4(zgv[0], zgv[1], zgv[2], zgv[3]);
        *(float4*)(&zl[r][tcol]) = make_float4(zlv[0], zlv[1], zlv[2], zlv[3]);
        if (any) atomicOr(&hasNbSh[r], 1);
    }
    __syncthreads();

    // ---------- phase 2: per-wave (wave w owns row w) ----------
    const int r = wid;
    const int s_r = sBase + r;
    const int row = rowBase + r;
    const float* msgB = messages + (size_t)b * SEQ_ * D_;
    const float* scnB = scn + (size_t)b * SEQ_ * NS_;

    float zr[16];
    // ----- geo sparsemax -----
#pragma unroll
    for (int i = 0; i < 16; ++i) zr[i] = zg[r][(i << 6) + lane];
    float mx = zr[0];
#pragma unroll
    for (int i = 1; i < 16; ++i) mx = fmaxf(mx, zr[i]);
#pragma unroll
    for (int off = 32; off; off >>= 1) mx = fmaxf(mx, __shfl_xor(mx, off, 64));
    float lo = mx - 1.f, hi = mx;
    for (int it = 0; it < 28; ++it) {
        const float mid = 0.5f * (lo + hi);
        float p = 0.f;
#pragma unroll
        for (int i = 0; i < 16; ++i) p += fmaxf(zr[i] - mid, 0.f);
        p = waveSum(p);
        if (p > 1.f) lo = mid; else hi = mid;
    }
    const float tauG = 0.5f * (lo + hi);
    float ax = 0.f, ay = 0.f, az = 0.f, aw = 0.f;
#pragma unroll
    for (int i = 0; i < 16; ++i) {
        const float wv = zr[i] - tauG;
        unsigned long long mbit = __ballot(wv > 0.f);
        while (mbit) {
            const int src = __ffsll((unsigned long long)mbit) - 1;
            mbit &= mbit - 1;
            const float wgt = __shfl(wv, src, 64);
            const float4 m4 = *(const float4*)(msgB + (size_t)((i << 6) + src) * D_ + (lane << 2));
            ax = fmaf(wgt, m4.x, ax); ay = fmaf(wgt, m4.y, ay);
            az = fmaf(wgt, m4.z, az); aw = fmaf(wgt, m4.w, aw);
        }
    }

    // ----- local sparsemax -----
    const int hasNb = hasNbSh[r];
#pragma unroll
    for (int i = 0; i < 16; ++i) {
        float z = zl[r][(i << 6) + lane];
        if (!hasNb) {
            const int t = (i << 6) + lane;
            z = (z <= -49999.f) ? BLKNEG_ : -0.05f * fabsf((float)(s_r - t));
        }
        zr[i] = z;
    }
    mx = zr[0];
#pragma unroll
    for (int i = 1; i < 16; ++i) mx = fmaxf(mx, zr[i]);
#pragma unroll
    for (int off = 32; off; off >>= 1) mx = fmaxf(mx, __shfl_xor(mx, off, 64));
    lo = mx - 1.f; hi = mx;
    for (int it = 0; it < 28; ++it) {
        const float mid = 0.5f * (lo + hi);
        float p = 0.f;
#pragma unroll
        for (int i = 0; i < 16; ++i) p += fmaxf(zr[i] - mid, 0.f);
        p = waveSum(p);
        if (p > 1.f) lo = mid; else hi = mid;
    }
    const float tauL = 0.5f * (lo + hi);
    float bx = 0.f, by = 0.f, bz = 0.f, bw = 0.f;
#pragma unroll
    for (int i = 0; i < 16; ++i) {
        const float wv = zr[i] - tauL;
        unsigned long long mbit = __ballot(wv > 0.f);
        while (mbit) {
            const int src = __ffsll((unsigned long long)mbit) - 1;
            mbit &= mbit - 1;
            const float wgt = __shfl(wv, src, 64);
            const float4 m4 = *(const float4*)(msgB + (size_t)((i << 6) + src) * D_ + (lane << 2));
            bx = fmaf(wgt, m4.x, bx); by = fmaf(wgt, m4.y, by);
            bz = fmaf(wgt, m4.z, bz); bw = fmaf(wgt, m4.w, bw);
        }
    }

    // ----- static neighbor-vocab branch -----
    const int q = x_ids[row];
    int nb[KNB_];
#pragma unroll
    for (int k = 0; k < KNB_; ++k) nb[k] = static_nb[(size_t)q * KNB_ + k];
    const float ss_l = scnB[(size_t)s_r * NS_ + lane];
    float simk[KNB_] = {};
    int cntk[KNB_] = {};
    int mcW = 0;
    const int* xb = x_ids + (b << 10);
    for (int pb = 0; pb <= s_r; pb += 64) {
        const int p = pb + lane;
        const int id = (p <= s_r) ? xb[p] : -1;
#pragma unroll
        for (int k = 0; k < KNB_; ++k) {
            unsigned long long mbit = __ballot(id == nb[k]);
            if (mbit) {
                cntk[k] += __popcll(mbit);
                while (mbit) {
                    const int src = __ffsll((unsigned long long)mbit) - 1;
                    mbit &= mbit - 1;
                    const int pp = pb + src;
                    float pv = scnB[(size_t)pp * NS_ + lane] * ss_l;
                    pv = waveSum(pv);
                    simk[k] += pv;
                    if (mcW < 64) { if (lane == 0) mlist[r][mcW] = (pp << 3) | k; ++mcW; }
                }
            }
        }
    }
    // edge MLP: lane = k*8 + j computes one gelu term
    const int kk = lane >> 3, jjn = lane & 7;
    float sv = simk[0];
#pragma unroll
    for (int k = 1; k < KNB_; ++k) sv = (kk == k) ? simk[k] : sv;
    const float xx = sv * W_e1[jjn] + b_e1[jjn];
    float eo = 0.5f * xx * (1.f + erff(xx * 0.70710678118654752f)) * W_e2[jjn];
    eo += __shfl_xor(eo, 1, 64); eo += __shfl_xor(eo, 2, 64); eo += __shfl_xor(eo, 4, 64);
    eo += b_e2[0];                              // edge[kk], replicated in group
    float m2 = eo;
    m2 = fmaxf(m2, __shfl_xor(m2, 8, 64));
    m2 = fmaxf(m2, __shfl_xor(m2, 16, 64));
    m2 = fmaxf(m2, __shfl_xor(m2, 32, 64));
    const float exv = expf(eo - m2);
    float smv = exv;
    smv += __shfl_xor(smv, 8, 64); smv += __shfl_xor(smv, 16, 64); smv += __shfl_xor(smv, 32, 64);
    const float ewk = exv / smv;                // softmax weight for this lane's kk

    float cov = 0.f;
#pragma unroll
    for (int k = 0; k < KNB_; ++k) cov += fminf((float)cntk[k], 1.f);
    cov *= 0.125f;

    float cx = 0.f, cy = 0.f, cz = 0.f, cw = 0.f;
    const int nm = (mcW < 64) ? mcW : 64;
    for (int i2 = 0; i2 < nm; ++i2) {
        const int ee = mlist[r][i2];
        const int pp = ee >> 3, k2 = ee & 7;
        const float wgt = __shfl(ewk, k2 << 3, 64);
        const float4 m4 = *(const float4*)(msgB + (size_t)pp * D_ + (lane << 2));
        cx = fmaf(wgt, m4.x, cx); cy = fmaf(wgt, m4.y, cy);
        cz = fmaf(wgt, m4.z, cz); cw = fmaf(wgt, m4.w, cw);
    }

    // ----- gated fusion epilogue -----
    const float gw = wsGw[row];
    const float icov = 1.f - cov, igw = 1.f - gw;
    const float fx = gw * ax + igw * (cov * cx + icov * bx);
    const float fy = gw * ay + igw * (cov * cy + icov * by);
    const float fz = gw * az + igw * (cov * cz + icov * bz);
    const float fw = gw * aw + igw * (cov * cw + icov * bw);
    float ssq = fx * fx + fy * fy + fz * fz + fw * fw;
    ssq = waveSum(ssq);
    const float nrm = fmaxf(sqrtf(ssq), 1e-12f);
    const float4 pr = *(const float4*)(wsProbe + (size_t)row * D_ + (lane << 2));
    float dp = (fx * pr.x + fy * pr.y + fz * pr.z + fw * pr.w) / nrm;
    dp = waveSum(dp);
    const float rel = 1.f / (1.f + expf(-dp));
    *(float4*)(out + (size_t)row * D_ + (lane << 2)) =
        make_float4(fx * rel, fy * rel, fz * rel, fw * rel);
}

extern "C" void kernel_launch(void* const* d_in, const int* in_sizes, int n_in,
                              void* d_out, int out_size, void* d_ws, size_t ws_size,
                              hipStream_t stream) {
    const float* messages  = (const float*)d_in[0];
    const float* hidden    = (const float*)d_in[1];
    const int*   x_ids     = (const int*)d_in[2];
    const float* scn       = (const float*)d_in[3];
    const void*  mask      = d_in[4];
    const int*   static_nb = (const int*)d_in[5];
    const float* gvel      = (const float*)d_in[6];
    const float* ctx       = (const float*)d_in[7];
    const float* ent       = (const float*)d_in[8];
    const float* W_vel     = (const float*)d_in[9];
    const float* W_e1      = (const float*)d_in[10];
    const float* b_e1      = (const float*)d_in[11];
    const float* W_e2      = (const float*)d_in[12];
    const float* b_e2      = (const float*)d_in[13];
    const float* W_probe   = (const float*)d_in[14];
    const float* W_gate    = (const float*)d_in[15];
    const float* b_gate    = (const float*)d_in[16];
    float* out = (float*)d_out;
    (void)in_sizes; (void)n_in; (void)out_size; (void)ws_size;

    char* ws = (char*)d_ws;
    size_t o = 0;
    int* flag      = (int*)(ws + o);   o += 256;
    float* wsEnd   = (float*)(ws + o); o += (size_t)B_ * SEQ_ * NS_ * 4;
    float* wsHa    = (float*)(ws + o); o += (size_t)B_ * SEQ_ * D_ * 4;
    float* wsProbe = (float*)(ws + o); o += (size_t)B_ * SEQ_ * D_ * 4;
    int* wsMode    = (int*)(ws + o);   o += (size_t)B_ * SEQ_ * 4;
    float* wsHn    = (float*)(ws + o); o += (size_t)B_ * SEQ_ * 4;
    float* wsGw    = (float*)(ws + o); o += (size_t)B_ * SEQ_ * 4;
    float* msgT    = (float*)(ws + o); o += (size_t)B_ * D_ * SEQ_ * 4;
    float* scnT    = (float*)(ws + o); o += (size_t)B_ * NS_ * SEQ_ * 4;
    float* WpT     = (float*)(ws + o); o += (size_t)D_ * D_ * 4;
    float* WvT     = (float*)(ws + o); o += (size_t)D_ * NS_ * 4;

    detect_mask_kernel<<<dim3(1), dim3(256), 0, stream>>>((const unsigned int*)mask, flag);
    transpose_kernel<<<dim3(D_ / 32, SEQ_ / 32, B_), dim3(32, 8), 0, stream>>>(messages, msgT, SEQ_, D_);
    transpose_kernel<<<dim3(NS_ / 32, SEQ_ / 32, B_), dim3(32, 8), 0, stream>>>(scn, scnT, SEQ_, NS_);
    transpose_kernel<<<dim3(D_ / 32, D_ / 32, 1), dim3(32, 8), 0, stream>>>(W_probe, WpT, D_, D_);
    transpose_kernel<<<dim3(NS_ / 32, D_ / 32, 1), dim3(32, 8), 0, stream>>>(W_vel, WvT, D_, NS_);
    precompute_light<<<dim3(B_ * SEQ_), dim3(256), 0, stream>>>(
        hidden, scn, gvel, ctx, ent, WvT, W_gate, b_gate,
        wsEnd, wsHa, wsMode, wsHn, wsGw);
    probe4_kernel<<<dim3(B_ * SEQ_ / 4), dim3(256), 0, stream>>>(hidden, WpT, wsProbe);
    row4_kernel<<<dim3(B_ * SEQ_ / 4), dim3(256), 0, stream>>>(
        messages, msgT, scnT, scn, x_ids, mask, static_nb,
        W_e1, b_e1, W_e2, b_e2,
        wsEnd, wsHa, wsProbe, wsMode, wsHn, wsGw, flag, out);
}

// Round 3
// 234.367 us; speedup vs baseline: 4.6691x; 1.0264x over previous
//
#include <hip/hip_runtime.h>
#include <math.h>

#define D_ 256
#define NS_ 64
#define KNB_ 8
#define SEQ_ 1024
#define B_ 4
#define NEG_ (-10000.0f)
#define BLKNEG_ (-50000.0f)

__device__ __forceinline__ float waveSum(float v) {
#pragma unroll
    for (int off = 32; off; off >>= 1) v += __shfl_xor(v, off, 64);
    return v;
}

__device__ __forceinline__ float blockSum(float v, float* scr) {
    const int tid = threadIdx.x;
    const int wid = tid >> 6, lane = tid & 63;
    v = waveSum(v);
    __syncthreads();
    if (lane == 0) scr[wid] = v;
    __syncthreads();
    return scr[0] + scr[1] + scr[2] + scr[3];
}

// One kernel: 4 transposes + mask-dtype detection.
// blocks [0,1024): messages [S][D] -> msgT [D][S] per batch
// blocks [1024,1280): scn [S][NS] -> scnT [NS][S] per batch
// blocks [1280,1344): W_probe [D][D] -> WpT
// blocks [1344,1360): W_vel [D][NS] -> WvT
// block 1360: mask dtype detect (0=int32, 1=uint8, 2=float32)
__global__ __launch_bounds__(256) void transpose_all(
    const float* __restrict__ messages, const float* __restrict__ scn,
    const float* __restrict__ W_probe, const float* __restrict__ W_vel,
    float* __restrict__ msgT, float* __restrict__ scnT,
    float* __restrict__ WpT, float* __restrict__ WvT,
    const unsigned int* __restrict__ maskW, int* __restrict__ flag)
{
    __shared__ float tile[32][33];
    __shared__ int notI, notF;
    const int bid = blockIdx.x;
    const int tx = threadIdx.x, ty = threadIdx.y;

    if (bid == 1360) {
        const int tid = ty * 32 + tx;
        if (tid == 0) { notI = 0; notF = 0; }
        __syncthreads();
        int ni = 0, nf = 0;
        for (int i = tid; i < 1024; i += 256) {
            const unsigned int w = maskW[i];
            if (w != 0u && w != 1u) ni = 1;
            if (w != 0u && w != 0x3f800000u) nf = 1;
        }
        if (ni) atomicOr(&notI, 1);
        if (nf) atomicOr(&notF, 1);
        __syncthreads();
        if (tid == 0) *flag = (!notI) ? 0 : ((!notF) ? 2 : 1);
        return;
    }

    const float* src; float* dst; int Rr, Cc, bz, cx, cy;
    if (bid < 1024) {
        const int i = bid; bz = i >> 8; const int rem = i & 255;
        cy = rem >> 3; cx = rem & 7;
        src = messages; dst = msgT; Rr = SEQ_; Cc = D_;
    } else if (bid < 1280) {
        const int i = bid - 1024; bz = i >> 6; const int rem = i & 63;
        cy = rem >> 1; cx = rem & 1;
        src = scn; dst = scnT; Rr = SEQ_; Cc = NS_;
    } else if (bid < 1344) {
        const int i = bid - 1280; bz = 0; cy = i >> 3; cx = i & 7;
        src = W_probe; dst = WpT; Rr = D_; Cc = D_;
    } else {
        const int i = bid - 1344; bz = 0; cy = i >> 1; cx = i & 1;
        src = W_vel; dst = WvT; Rr = D_; Cc = NS_;
    }
    const int c0 = cx << 5, r0 = cy << 5;
    const float* s = src + (size_t)bz * Rr * Cc;
    float* d = dst + (size_t)bz * Rr * Cc;
#pragma unroll
    for (int i = 0; i < 32; i += 8)
        tile[ty + i][tx] = s[(size_t)(r0 + ty + i) * Cc + c0 + tx];
    __syncthreads();
#pragma unroll
    for (int i = 0; i < 32; i += 8)
        d[(size_t)(c0 + ty + i) * Rr + r0 + tx] = tile[tx][ty + i];
}

__global__ __launch_bounds__(256) void precompute_light(
    const float* __restrict__ hidden,
    const float* __restrict__ scn,
    const float* __restrict__ gvel,
    const float* __restrict__ ctx,
    const float* __restrict__ ent,
    const float* __restrict__ WvT,     // [NS][D]
    const float* __restrict__ W_gate,
    const float* __restrict__ b_gate,
    float* __restrict__ wsEnd,
    float* __restrict__ wsHa,
    int* __restrict__ wsMode,
    float* __restrict__ wsHn,
    float* __restrict__ wsGw)
{
    __shared__ float scr[4];
    const int row = blockIdx.x;
    const int tid = threadIdx.x;

    if (tid < 64) {   // wave0: endpoint normalize + argmax mode
        const float sv = scn[(size_t)row * NS_ + tid];
        const float gv = gvel[(size_t)row * NS_ + tid];
        const float e = sv + 0.4f * gv;
        const float ss = waveSum(e * e);
        wsEnd[(size_t)row * NS_ + tid] = e / fmaxf(sqrtf(ss), 1e-12f);
        float v = sv; int idx = tid;
#pragma unroll
        for (int off = 1; off < 64; off <<= 1) {
            const float ov = __shfl_xor(v, off, 64);
            const int   oi = __shfl_xor(idx, off, 64);
            if (ov > v || (ov == v && oi < idx)) { v = ov; idx = oi; }
        }
        if (tid == 0) wsMode[row] = idx;
    }

    // vel_h[tid] = sum_e gvel_row[e] * WvT[e][tid]   (gvel uniform -> s_load)
    const float* gRow = gvel + (size_t)row * NS_;
    float vh = 0.f;
#pragma unroll
    for (int e = 0; e < NS_; e += 4) {
        const float4 g4 = *(const float4*)(gRow + e);
        vh = fmaf(g4.x, WvT[(size_t)(e + 0) * D_ + tid],
             fmaf(g4.y, WvT[(size_t)(e + 1) * D_ + tid],
             fmaf(g4.z, WvT[(size_t)(e + 2) * D_ + tid],
             fmaf(g4.w, WvT[(size_t)(e + 3) * D_ + tid], vh))));
    }
    const float hd = hidden[(size_t)row * D_ + tid];
    const float ha = hd + 0.3f * vh;
    const float ssA = blockSum(ha * ha, scr);
    wsHa[(size_t)row * D_ + tid] = ha / fmaxf(sqrtf(ssA), 1e-12f);

    const float gd = blockSum(hd * W_gate[tid], scr);
    if (tid == 0) {
        const float raw = 1.f / (1.f + expf(-(gd + b_gate[0])));
        wsGw[row] = raw * ctx[row];
        wsHn[row] = ent[row] / 10.373491191781864f;   // log(32000)+1e-8
    }
}

// probe = normalize(hidden @ W_probe^T), 4 rows per block via transposed W_probe
__global__ __launch_bounds__(256, 4) void probe4_kernel(
    const float* __restrict__ hidden,
    const float* __restrict__ WpT,     // [D][D] = W_probe^T
    float* __restrict__ wsProbe)
{
    __shared__ float scr[4];
    const int rowBase = blockIdx.x << 2;
    const int tid = threadIdx.x;
    const float* h0 = hidden + (size_t)rowBase * D_;
    float acc[4] = {0.f, 0.f, 0.f, 0.f};
    for (int e = 0; e < D_; e += 4) {
        const float w0 = WpT[(size_t)(e + 0) * D_ + tid];
        const float w1 = WpT[(size_t)(e + 1) * D_ + tid];
        const float w2 = WpT[(size_t)(e + 2) * D_ + tid];
        const float w3 = WpT[(size_t)(e + 3) * D_ + tid];
#pragma unroll
        for (int r = 0; r < 4; ++r) {
            const float4 h4 = *(const float4*)(h0 + (size_t)r * D_ + e);  // uniform
            acc[r] = fmaf(h4.x, w0, fmaf(h4.y, w1, fmaf(h4.z, w2, fmaf(h4.w, w3, acc[r]))));
        }
    }
#pragma unroll
    for (int r = 0; r < 4; ++r) {
        const float ssq = blockSum(acc[r] * acc[r], scr);
        wsProbe[(size_t)(rowBase + r) * D_ + tid] = acc[r] / fmaxf(sqrtf(ssq), 1e-12f);
    }
}

__global__ __launch_bounds__(256, 4) void row4_kernel(
    const float* __restrict__ messages,
    const float* __restrict__ msgT,     // [B][D][S]
    const float* __restrict__ scnT,     // [B][NS][S]
    const float* __restrict__ scn,
    const int* __restrict__ x_ids,
    const void* __restrict__ maskP,
    const int* __restrict__ static_nb,
    const float* __restrict__ W_e1,
    const float* __restrict__ b_e1,
    const float* __restrict__ W_e2,
    const float* __restrict__ b_e2,
    const float* __restrict__ wsEnd,
    const float* __restrict__ wsHa,
    const float* __restrict__ wsProbe,
    const int* __restrict__ wsMode,
    const float* __restrict__ wsHn,
    const float* __restrict__ wsGw,
    const int* __restrict__ maskFlag,
    float* __restrict__ out)
{
    __shared__ float zg[4][SEQ_];
    __shared__ float zl[4][SEQ_];
    __shared__ int   mlist[4][64];
    __shared__ int   hasNbSh[4];

    // XCD-aware swizzle: XCD pair {2b,2b+1} handles batch b (L2 working set fits)
    const int bid = blockIdx.x;
    const int xcd = bid & 7, jj0 = bid >> 3;
    const int b = xcd >> 1;
    const int sBase = (((xcd & 1) << 7) + jj0) << 2;   // 4 rows per block
    const int rowBase = (b << 10) + sBase;

    const int tid = threadIdx.x;
    const int wid = tid >> 6, lane = tid & 63;

    if (tid < 4) hasNbSh[tid] = 0;
    __syncthreads();

    // ---------- phase 1: z = sims via register-tiled GEMM over transposed operands ----------
    const float* msgTb = msgT + (size_t)b * D_ * SEQ_;
    const float* scnTb = scnT + (size_t)b * NS_ * SEQ_;
    const float* hA = wsHa + (size_t)rowBase * D_;     // 4 rows, wave-uniform reads
    const float* eA = wsEnd + (size_t)rowBase * NS_;
    const float* sA = scn + (size_t)rowBase * NS_;
    const int tcol = tid << 2;                         // this thread's 4 t's

    float zh[4][4] = {}; float ze[4][4] = {}; float zs[4][4] = {};
    for (int dc = 0; dc < D_; dc += 4) {
        float4 mv[4];
#pragma unroll
        for (int dj = 0; dj < 4; ++dj)
            mv[dj] = *(const float4*)(msgTb + (size_t)(dc + dj) * SEQ_ + tcol);
#pragma unroll
        for (int r = 0; r < 4; ++r) {
            const float4 h4 = *(const float4*)(hA + (size_t)r * D_ + dc);   // uniform
            const float hx[4] = {h4.x, h4.y, h4.z, h4.w};
#pragma unroll
            for (int dj = 0; dj < 4; ++dj) {
                zh[r][0] = fmaf(hx[dj], mv[dj].x, zh[r][0]);
                zh[r][1] = fmaf(hx[dj], mv[dj].y, zh[r][1]);
                zh[r][2] = fmaf(hx[dj], mv[dj].z, zh[r][2]);
                zh[r][3] = fmaf(hx[dj], mv[dj].w, zh[r][3]);
            }
        }
    }
    for (int dc = 0; dc < NS_; dc += 4) {
        float4 sv[4];
#pragma unroll
        for (int dj = 0; dj < 4; ++dj)
            sv[dj] = *(const float4*)(scnTb + (size_t)(dc + dj) * SEQ_ + tcol);
#pragma unroll
        for (int r = 0; r < 4; ++r) {
            const float4 e4 = *(const float4*)(eA + (size_t)r * NS_ + dc);  // uniform
            const float4 s4 = *(const float4*)(sA + (size_t)r * NS_ + dc);  // uniform
            const float ex[4] = {e4.x, e4.y, e4.z, e4.w};
            const float sx[4] = {s4.x, s4.y, s4.z, s4.w};
#pragma unroll
            for (int dj = 0; dj < 4; ++dj) {
                ze[r][0] = fmaf(ex[dj], sv[dj].x, ze[r][0]);
                ze[r][1] = fmaf(ex[dj], sv[dj].y, ze[r][1]);
                ze[r][2] = fmaf(ex[dj], sv[dj].z, ze[r][2]);
                ze[r][3] = fmaf(ex[dj], sv[dj].w, ze[r][3]);
                zs[r][0] = fmaf(sx[dj], sv[dj].x, zs[r][0]);
                zs[r][1] = fmaf(sx[dj], sv[dj].y, zs[r][1]);
                zs[r][2] = fmaf(sx[dj], sv[dj].z, zs[r][2]);
                zs[r][3] = fmaf(sx[dj], sv[dj].w, zs[r][3]);
            }
        }
    }

    // ---------- z-write: mask + mode, store to LDS ----------
    const int mf = *maskFlag;
    const int4 md = *(const int4*)(wsMode + (b << 10) + tcol);
    const int mdx[4] = {md.x, md.y, md.z, md.w};
#pragma unroll
    for (int r = 0; r < 4; ++r) {
        const int s_r = sBase + r;
        const float Hn = wsHn[rowBase + r];
        const int mS = wsMode[rowBase + r];
        int blk[4];
        const size_t mb = (size_t)s_r * SEQ_ + tcol;
        if (mf == 1) {
            const uchar4 m = *(const uchar4*)((const unsigned char*)maskP + mb);
            blk[0] = m.x != 0; blk[1] = m.y != 0; blk[2] = m.z != 0; blk[3] = m.w != 0;
        } else if (mf == 2) {
            const float4 m = *(const float4*)((const float*)maskP + mb);
            blk[0] = m.x != 0.f; blk[1] = m.y != 0.f; blk[2] = m.z != 0.f; blk[3] = m.w != 0.f;
        } else {
            const int4 m = *(const int4*)((const int*)maskP + mb);
            blk[0] = m.x != 0; blk[1] = m.y != 0; blk[2] = m.z != 0; blk[3] = m.w != 0;
        }
        const int dlt = s_r - tcol;
        if ((unsigned)dlt < 4u) blk[dlt] = 1;
        float zgv[4], zlv[4];
        int any = 0;
#pragma unroll
        for (int j = 0; j < 4; ++j) {
            zgv[j] = blk[j] ? NEG_ : (ze[r][j] * Hn + 0.5f * zh[r][j]) * 5.0f;
            const int sm = (!blk[j]) && (mdx[j] == mS);
            any |= sm;
            zlv[j] = sm ? zs[r][j] * 5.0f : (blk[j] ? BLKNEG_ : 0.0f);
        }
        *(float4*)(&zg[r][tcol]) = make_float4(zgv[0], zgv[1], zgv[2], zgv[3]);
        *(float4*)(&zl[r][tcol]) = make_float4(zlv[0], zlv[1], zlv[2], zlv[3]);
        if (any) atomicOr(&hasNbSh[r], 1);
    }
    __syncthreads();

    // ---------- phase 2: per-wave (wave w owns row w) ----------
    const int r = wid;
    const int s_r = sBase + r;
    const int row = rowBase + r;
    const float* msgB = messages + (size_t)b * SEQ_ * D_;
    const float* scnB = scn + (size_t)b * SEQ_ * NS_;

    float zr[16];
    // ----- geo sparsemax -----
#pragma unroll
    for (int i = 0; i < 16; ++i) zr[i] = zg[r][(i << 6) + lane];
    float mx = zr[0];
#pragma unroll
    for (int i = 1; i < 16; ++i) mx = fmaxf(mx, zr[i]);
#pragma unroll
    for (int off = 32; off; off >>= 1) mx = fmaxf(mx, __shfl_xor(mx, off, 64));
    float lo = mx - 1.f, hi = mx;
    for (int it = 0; it < 28; ++it) {
        const float mid = 0.5f * (lo + hi);
        float p = 0.f;
#pragma unroll
        for (int i = 0; i < 16; ++i) p += fmaxf(zr[i] - mid, 0.f);
        p = waveSum(p);
        if (p > 1.f) lo = mid; else hi = mid;
    }
    const float tauG = 0.5f * (lo + hi);
    float ax = 0.f, ay = 0.f, az = 0.f, aw = 0.f;
#pragma unroll
    for (int i = 0; i < 16; ++i) {
        const float wv = zr[i] - tauG;
        unsigned long long mbit = __ballot(wv > 0.f);
        while (mbit) {
            const int src = __ffsll((unsigned long long)mbit) - 1;
            mbit &= mbit - 1;
            const float wgt = __shfl(wv, src, 64);
            const float4 m4 = *(const float4*)(msgB + (size_t)((i << 6) + src) * D_ + (lane << 2));
            ax = fmaf(wgt, m4.x, ax); ay = fmaf(wgt, m4.y, ay);
            az = fmaf(wgt, m4.z, az); aw = fmaf(wgt, m4.w, aw);
        }
    }

    // ----- local sparsemax -----
    const int hasNb = hasNbSh[r];
#pragma unroll
    for (int i = 0; i < 16; ++i) {
        float z = zl[r][(i << 6) + lane];
        if (!hasNb) {
            const int t = (i << 6) + lane;
            z = (z <= -49999.f) ? BLKNEG_ : -0.05f * fabsf((float)(s_r - t));
        }
        zr[i] = z;
    }
    mx = zr[0];
#pragma unroll
    for (int i = 1; i < 16; ++i) mx = fmaxf(mx, zr[i]);
#pragma unroll
    for (int off = 32; off; off >>= 1) mx = fmaxf(mx, __shfl_xor(mx, off, 64));
    lo = mx - 1.f; hi = mx;
    for (int it = 0; it < 28; ++it) {
        const float mid = 0.5f * (lo + hi);
        float p = 0.f;
#pragma unroll
        for (int i = 0; i < 16; ++i) p += fmaxf(zr[i] - mid, 0.f);
        p = waveSum(p);
        if (p > 1.f) lo = mid; else hi = mid;
    }
    const float tauL = 0.5f * (lo + hi);
    float bx = 0.f, by = 0.f, bz = 0.f, bw = 0.f;
#pragma unroll
    for (int i = 0; i < 16; ++i) {
        const float wv = zr[i] - tauL;
        unsigned long long mbit = __ballot(wv > 0.f);
        while (mbit) {
            const int src = __ffsll((unsigned long long)mbit) - 1;
            mbit &= mbit - 1;
            const float wgt = __shfl(wv, src, 64);
            const float4 m4 = *(const float4*)(msgB + (size_t)((i << 6) + src) * D_ + (lane << 2));
            bx = fmaf(wgt, m4.x, bx); by = fmaf(wgt, m4.y, by);
            bz = fmaf(wgt, m4.z, bz); bw = fmaf(wgt, m4.w, bw);
        }
    }

    // ----- static neighbor-vocab branch -----
    const int q = x_ids[row];
    int nb[KNB_];
#pragma unroll
    for (int k = 0; k < KNB_; ++k) nb[k] = static_nb[(size_t)q * KNB_ + k];
    const float ss_l = scnB[(size_t)s_r * NS_ + lane];
    float simk[KNB_] = {};
    int cntk[KNB_] = {};
    int mcW = 0;
    const int* xb = x_ids + (b << 10);
    for (int pb = 0; pb <= s_r; pb += 64) {
        const int p = pb + lane;
        const int id = (p <= s_r) ? xb[p] : -1;
#pragma unroll
        for (int k = 0; k < KNB_; ++k) {
            unsigned long long mbit = __ballot(id == nb[k]);
            if (mbit) {
                cntk[k] += __popcll(mbit);
                while (mbit) {
                    const int src = __ffsll((unsigned long long)mbit) - 1;
                    mbit &= mbit - 1;
                    const int pp = pb + src;
                    float pv = scnB[(size_t)pp * NS_ + lane] * ss_l;
                    pv = waveSum(pv);
                    simk[k] += pv;
                    if (mcW < 64) { if (lane == 0) mlist[r][mcW] = (pp << 3) | k; ++mcW; }
                }
            }
        }
    }
    // edge MLP: lane = k*8 + j computes one gelu term
    const int kk = lane >> 3, jjn = lane & 7;
    float sv = simk[0];
#pragma unroll
    for (int k = 1; k < KNB_; ++k) sv = (kk == k) ? simk[k] : sv;
    const float xx = sv * W_e1[jjn] + b_e1[jjn];
    float eo = 0.5f * xx * (1.f + erff(xx * 0.70710678118654752f)) * W_e2[jjn];
    eo += __shfl_xor(eo, 1, 64); eo += __shfl_xor(eo, 2, 64); eo += __shfl_xor(eo, 4, 64);
    eo += b_e2[0];                              // edge[kk], replicated in group
    float m2 = eo;
    m2 = fmaxf(m2, __shfl_xor(m2, 8, 64));
    m2 = fmaxf(m2, __shfl_xor(m2, 16, 64));
    m2 = fmaxf(m2, __shfl_xor(m2, 32, 64));
    const float exv = expf(eo - m2);
    float smv = exv;
    smv += __shfl_xor(smv, 8, 64); smv += __shfl_xor(smv, 16, 64); smv += __shfl_xor(smv, 32, 64);
    const float ewk = exv / smv;                // softmax weight for this lane's kk

    float cov = 0.f;
#pragma unroll
    for (int k = 0; k < KNB_; ++k) cov += fminf((float)cntk[k], 1.f);
    cov *= 0.125f;

    float cx = 0.f, cy = 0.f, cz = 0.f, cw = 0.f;
    const int nm = (mcW < 64) ? mcW : 64;
    for (int i2 = 0; i2 < nm; ++i2) {
        const int ee = mlist[r][i2];
        const int pp = ee >> 3, k2 = ee & 7;
        const float wgt = __shfl(ewk, k2 << 3, 64);
        const float4 m4 = *(const float4*)(msgB + (size_t)pp * D_ + (lane << 2));
        cx = fmaf(wgt, m4.x, cx); cy = fmaf(wgt, m4.y, cy);
        cz = fmaf(wgt, m4.z, cz); cw = fmaf(wgt, m4.w, cw);
    }

    // ----- gated fusion epilogue -----
    const float gw = wsGw[row];
    const float icov = 1.f - cov, igw = 1.f - gw;
    const float fx = gw * ax + igw * (cov * cx + icov * bx);
    const float fy = gw * ay + igw * (cov * cy + icov * by);
    const float fz = gw * az + igw * (cov * cz + icov * bz);
    const float fw = gw * aw + igw * (cov * cw + icov * bw);
    float ssq = fx * fx + fy * fy + fz * fz + fw * fw;
    ssq = waveSum(ssq);
    const float nrm = fmaxf(sqrtf(ssq), 1e-12f);
    const float4 pr = *(const float4*)(wsProbe + (size_t)row * D_ + (lane << 2));
    float dp = (fx * pr.x + fy * pr.y + fz * pr.z + fw * pr.w) / nrm;
    dp = waveSum(dp);
    const float rel = 1.f / (1.f + expf(-dp));
    *(float4*)(out + (size_t)row * D_ + (lane << 2)) =
        make_float4(fx * rel, fy * rel, fz * rel, fw * rel);
}

extern "C" void kernel_launch(void* const* d_in, const int* in_sizes, int n_in,
                              void* d_out, int out_size, void* d_ws, size_t ws_size,
                              hipStream_t stream) {
    const float* messages  = (const float*)d_in[0];
    const float* hidden    = (const float*)d_in[1];
    const int*   x_ids     = (const int*)d_in[2];
    const float* scn       = (const float*)d_in[3];
    const void*  mask      = d_in[4];
    const int*   static_nb = (const int*)d_in[5];
    const float* gvel      = (const float*)d_in[6];
    const float* ctx       = (const float*)d_in[7];
    const float* ent       = (const float*)d_in[8];
    const float* W_vel     = (const float*)d_in[9];
    const float* W_e1      = (const float*)d_in[10];
    const float* b_e1      = (const float*)d_in[11];
    const float* W_e2      = (const float*)d_in[12];
    const float* b_e2      = (const float*)d_in[13];
    const float* W_probe   = (const float*)d_in[14];
    const float* W_gate    = (const float*)d_in[15];
    const float* b_gate    = (const float*)d_in[16];
    float* out = (float*)d_out;
    (void)in_sizes; (void)n_in; (void)out_size; (void)ws_size;

    char* ws = (char*)d_ws;
    size_t o = 0;
    int* flag      = (int*)(ws + o);   o += 256;
    float* wsEnd   = (float*)(ws + o); o += (size_t)B_ * SEQ_ * NS_ * 4;
    float* wsHa    = (float*)(ws + o); o += (size_t)B_ * SEQ_ * D_ * 4;
    float* wsProbe = (float*)(ws + o); o += (size_t)B_ * SEQ_ * D_ * 4;
    int* wsMode    = (int*)(ws + o);   o += (size_t)B_ * SEQ_ * 4;
    float* wsHn    = (float*)(ws + o); o += (size_t)B_ * SEQ_ * 4;
    float* wsGw    = (float*)(ws + o); o += (size_t)B_ * SEQ_ * 4;
    float* msgT    = (float*)(ws + o); o += (size_t)B_ * D_ * SEQ_ * 4;
    float* scnT    = (float*)(ws + o); o += (size_t)B_ * NS_ * SEQ_ * 4;
    float* WpT     = (float*)(ws + o); o += (size_t)D_ * D_ * 4;
    float* WvT     = (float*)(ws + o); o += (size_t)D_ * NS_ * 4;

    transpose_all<<<dim3(1361), dim3(32, 8), 0, stream>>>(
        messages, scn, W_probe, W_vel, msgT, scnT, WpT, WvT,
        (const unsigned int*)mask, flag);
    precompute_light<<<dim3(B_ * SEQ_), dim3(256), 0, stream>>>(
        hidden, scn, gvel, ctx, ent, WvT, W_gate, b_gate,
        wsEnd, wsHa, wsMode, wsHn, wsGw);
    probe4_kernel<<<dim3(B_ * SEQ_ / 4), dim3(256), 0, stream>>>(hidden, WpT, wsProbe);
    row4_kernel<<<dim3(B_ * SEQ_ / 4), dim3(256), 0, stream>>>(
        messages, msgT, scnT, scn, x_ids, mask, static_nb,
        W_e1, b_e1, W_e2, b_e2,
        wsEnd, wsHa, wsProbe, wsMode, wsHn, wsGw, flag, out);
}

// Round 4
// 201.421 us; speedup vs baseline: 5.4328x; 1.1636x over previous
//
#include <hip/hip_runtime.h>
#include <math.h>

#define D_ 256
#define NS_ 64
#define KNB_ 8
#define SEQ_ 1024
#define B_ 4
#define NEG_ (-10000.0f)
#define BLKNEG_ (-50000.0f)

__device__ __forceinline__ float waveSum(float v) {
#pragma unroll
    for (int off = 32; off; off >>= 1) v += __shfl_xor(v, off, 64);
    return v;
}

__device__ __forceinline__ void waveSum2(float& a, float& b) {
#pragma unroll
    for (int off = 32; off; off >>= 1) {
        a += __shfl_xor(a, off, 64);
        b += __shfl_xor(b, off, 64);
    }
}

__device__ __forceinline__ float blockSum(float v, float* scr) {
    const int tid = threadIdx.x;
    const int wid = tid >> 6, lane = tid & 63;
    v = waveSum(v);
    __syncthreads();
    if (lane == 0) scr[wid] = v;
    __syncthreads();
    return scr[0] + scr[1] + scr[2] + scr[3];
}

// exact sparsemax tau via support iteration (monotone, fixpoint = exact tau)
__device__ __forceinline__ float sparsemaxTauWave(const float* zr) {
    float mx = zr[0];
#pragma unroll
    for (int i = 1; i < 16; ++i) mx = fmaxf(mx, zr[i]);
#pragma unroll
    for (int off = 32; off; off >>= 1) mx = fmaxf(mx, __shfl_xor(mx, off, 64));
    float tau = mx - 1.0f;
    for (int it = 0; it < 32; ++it) {
        float ssum = 0.f, cnt = 0.f;
#pragma unroll
        for (int i = 0; i < 16; ++i) {
            if (zr[i] > tau) { ssum += zr[i]; cnt += 1.f; }
        }
        waveSum2(ssum, cnt);
        if (cnt < 0.5f) break;                 // cannot happen; safety
        const float nt = (ssum - 1.0f) / cnt;
        if (nt == tau) break;                  // support stable -> exact
        tau = nt;
    }
    return tau;
}

// 4 transposes + mask-dtype detection in one launch.
__global__ __launch_bounds__(256) void transpose_all(
    const float* __restrict__ messages, const float* __restrict__ scn,
    const float* __restrict__ W_probe, const float* __restrict__ W_vel,
    float* __restrict__ msgT, float* __restrict__ scnT,
    float* __restrict__ WpT, float* __restrict__ WvT,
    const unsigned int* __restrict__ maskW, int* __restrict__ flag)
{
    __shared__ float tile[32][33];
    __shared__ int notI, notF;
    const int bid = blockIdx.x;
    const int tx = threadIdx.x, ty = threadIdx.y;

    if (bid == 1360) {
        const int tid = ty * 32 + tx;
        if (tid == 0) { notI = 0; notF = 0; }
        __syncthreads();
        int ni = 0, nf = 0;
        for (int i = tid; i < 1024; i += 256) {
            const unsigned int w = maskW[i];
            if (w != 0u && w != 1u) ni = 1;
            if (w != 0u && w != 0x3f800000u) nf = 1;
        }
        if (ni) atomicOr(&notI, 1);
        if (nf) atomicOr(&notF, 1);
        __syncthreads();
        if (tid == 0) *flag = (!notI) ? 0 : ((!notF) ? 2 : 1);
        return;
    }

    const float* src; float* dst; int Rr, Cc, bz, cx, cy;
    if (bid < 1024) {
        const int i = bid; bz = i >> 8; const int rem = i & 255;
        cy = rem >> 3; cx = rem & 7;
        src = messages; dst = msgT; Rr = SEQ_; Cc = D_;
    } else if (bid < 1280) {
        const int i = bid - 1024; bz = i >> 6; const int rem = i & 63;
        cy = rem >> 1; cx = rem & 1;
        src = scn; dst = scnT; Rr = SEQ_; Cc = NS_;
    } else if (bid < 1344) {
        const int i = bid - 1280; bz = 0; cy = i >> 3; cx = i & 7;
        src = W_probe; dst = WpT; Rr = D_; Cc = D_;
    } else {
        const int i = bid - 1344; bz = 0; cy = i >> 1; cx = i & 1;
        src = W_vel; dst = WvT; Rr = D_; Cc = NS_;
    }
    const int c0 = cx << 5, r0 = cy << 5;
    const float* s = src + (size_t)bz * Rr * Cc;
    float* d = dst + (size_t)bz * Rr * Cc;
#pragma unroll
    for (int i = 0; i < 32; i += 8)
        tile[ty + i][tx] = s[(size_t)(r0 + ty + i) * Cc + c0 + tx];
    __syncthreads();
#pragma unroll
    for (int i = 0; i < 32; i += 8)
        d[(size_t)(c0 + ty + i) * Rr + r0 + tx] = tile[tx][ty + i];
}

// merged per-row prep: probe GEMV + vel GEMV + h_aimed norm + endpoint norm
// + argmax mode + gate + entropy norm.  4 rows per block.
__global__ __launch_bounds__(256) void prep4_kernel(
    const float* __restrict__ hidden,
    const float* __restrict__ scn,
    const float* __restrict__ gvel,
    const float* __restrict__ ctx,
    const float* __restrict__ ent,
    const float* __restrict__ WpT,     // [D][D]
    const float* __restrict__ WvT,     // [NS][D]
    const float* __restrict__ W_gate,
    const float* __restrict__ b_gate,
    float* __restrict__ wsEnd,
    float* __restrict__ wsHa,
    float* __restrict__ wsProbe,
    int* __restrict__ wsMode,
    float* __restrict__ wsHn,
    float* __restrict__ wsGw)
{
    __shared__ float scr[4];
    const int rowBase = blockIdx.x << 2;
    const int tid = threadIdx.x;
    const int wid = tid >> 6, lane = tid & 63;
    const float* h0 = hidden + (size_t)rowBase * D_;

    float pr[4] = {0.f, 0.f, 0.f, 0.f};
    for (int e = 0; e < D_; e += 4) {
        const float w0 = WpT[(size_t)(e + 0) * D_ + tid];
        const float w1 = WpT[(size_t)(e + 1) * D_ + tid];
        const float w2 = WpT[(size_t)(e + 2) * D_ + tid];
        const float w3 = WpT[(size_t)(e + 3) * D_ + tid];
#pragma unroll
        for (int r = 0; r < 4; ++r) {
            const float4 h4 = *(const float4*)(h0 + (size_t)r * D_ + e);
            pr[r] = fmaf(h4.x, w0, fmaf(h4.y, w1, fmaf(h4.z, w2, fmaf(h4.w, w3, pr[r]))));
        }
    }
    float vh[4] = {0.f, 0.f, 0.f, 0.f};
    for (int e = 0; e < NS_; e += 4) {
        const float w0 = WvT[(size_t)(e + 0) * D_ + tid];
        const float w1 = WvT[(size_t)(e + 1) * D_ + tid];
        const float w2 = WvT[(size_t)(e + 2) * D_ + tid];
        const float w3 = WvT[(size_t)(e + 3) * D_ + tid];
#pragma unroll
        for (int r = 0; r < 4; ++r) {
            const float4 g4 = *(const float4*)(gvel + (size_t)(rowBase + r) * NS_ + e);
            vh[r] = fmaf(g4.x, w0, fmaf(g4.y, w1, fmaf(g4.z, w2, fmaf(g4.w, w3, vh[r]))));
        }
    }

    // per-wave: wave r handles row r (endpoint, argmax, gate, Hn)
    {
        const int r = wid, row = rowBase + r;
        const float sv = scn[(size_t)row * NS_ + lane];
        const float gv = gvel[(size_t)row * NS_ + lane];
        const float e = sv + 0.4f * gv;
        const float ss = waveSum(e * e);
        wsEnd[(size_t)row * NS_ + lane] = e / fmaxf(sqrtf(ss), 1e-12f);
        float v = sv; int idx = lane;
#pragma unroll
        for (int off = 1; off < 64; off <<= 1) {
            const float ov = __shfl_xor(v, off, 64);
            const int   oi = __shfl_xor(idx, off, 64);
            if (ov > v || (ov == v && oi < idx)) { v = ov; idx = oi; }
        }
        float gd = 0.f;
#pragma unroll
        for (int j = 0; j < 4; ++j) {
            const int d = lane + (j << 6);
            gd = fmaf(h0[(size_t)r * D_ + d], W_gate[d], gd);
        }
        gd = waveSum(gd);
        if (lane == 0) {
            wsMode[row] = idx;
            const float raw = 1.f / (1.f + expf(-(gd + b_gate[0])));
            wsGw[row] = raw * ctx[row];
            wsHn[row] = ent[row] / 10.373491191781864f;   // log(32000)+1e-8
        }
    }

    // block-wide norms for h_aimed and probe
#pragma unroll
    for (int r = 0; r < 4; ++r) {
        const float ha = h0[(size_t)r * D_ + tid] + 0.3f * vh[r];
        const float ssA = blockSum(ha * ha, scr);
        wsHa[(size_t)(rowBase + r) * D_ + tid] = ha / fmaxf(sqrtf(ssA), 1e-12f);
        const float ssP = blockSum(pr[r] * pr[r], scr);
        wsProbe[(size_t)(rowBase + r) * D_ + tid] = pr[r] / fmaxf(sqrtf(ssP), 1e-12f);
    }
}

// Kernel A: all-pairs sims -> zg/zl  (pure streaming GEMM, 8 rows/block)
__global__ __launch_bounds__(512) void sims_kernel(
    const float* __restrict__ msgT,     // [B][D][S]
    const float* __restrict__ scnT,     // [B][NS][S]
    const float* __restrict__ scn,
    const float* __restrict__ wsHa,
    const float* __restrict__ wsEnd,
    const int* __restrict__ wsMode,
    const float* __restrict__ wsHn,
    const void* __restrict__ maskP,
    const int* __restrict__ maskFlag,
    float* __restrict__ zgO,            // [4096][1024]
    float* __restrict__ zlO)            // [4096][1024]
{
    const int bid = blockIdx.x;          // 512 blocks
    const int b = bid >> 7;
    const int sBase = (bid & 127) << 3;  // 8 rows
    const int rowBase = (b << 10) + sBase;
    const int tid = threadIdx.x;         // 0..511
    const int tcol = tid << 1;           // 2 cols

    const float* msgTb = msgT + (size_t)b * D_ * SEQ_;
    const float* scnTb = scnT + (size_t)b * NS_ * SEQ_;
    const float* hA = wsHa + (size_t)rowBase * D_;
    const float* eA = wsEnd + (size_t)rowBase * NS_;
    const float* sA = scn + (size_t)rowBase * NS_;

    float zh[8][2] = {};
    for (int dc = 0; dc < D_; dc += 4) {
        float2 mv[4];
#pragma unroll
        for (int dj = 0; dj < 4; ++dj)
            mv[dj] = *(const float2*)(msgTb + (size_t)(dc + dj) * SEQ_ + tcol);
#pragma unroll
        for (int r = 0; r < 8; ++r) {
            const float4 h4 = *(const float4*)(hA + (size_t)r * D_ + dc);  // uniform
            zh[r][0] = fmaf(h4.x, mv[0].x, fmaf(h4.y, mv[1].x,
                       fmaf(h4.z, mv[2].x, fmaf(h4.w, mv[3].x, zh[r][0]))));
            zh[r][1] = fmaf(h4.x, mv[0].y, fmaf(h4.y, mv[1].y,
                       fmaf(h4.z, mv[2].y, fmaf(h4.w, mv[3].y, zh[r][1]))));
        }
    }
    float ze[8][2] = {}; float zs[8][2] = {};
    for (int dc = 0; dc < NS_; dc += 4) {
        float2 sv[4];
#pragma unroll
        for (int dj = 0; dj < 4; ++dj)
            sv[dj] = *(const float2*)(scnTb + (size_t)(dc + dj) * SEQ_ + tcol);
#pragma unroll
        for (int r = 0; r < 8; ++r) {
            const float4 e4 = *(const float4*)(eA + (size_t)r * NS_ + dc);  // uniform
            const float4 s4 = *(const float4*)(sA + (size_t)r * NS_ + dc);  // uniform
            ze[r][0] = fmaf(e4.x, sv[0].x, fmaf(e4.y, sv[1].x,
                       fmaf(e4.z, sv[2].x, fmaf(e4.w, sv[3].x, ze[r][0]))));
            ze[r][1] = fmaf(e4.x, sv[0].y, fmaf(e4.y, sv[1].y,
                       fmaf(e4.z, sv[2].y, fmaf(e4.w, sv[3].y, ze[r][1]))));
            zs[r][0] = fmaf(s4.x, sv[0].x, fmaf(s4.y, sv[1].x,
                       fmaf(s4.z, sv[2].x, fmaf(s4.w, sv[3].x, zs[r][0]))));
            zs[r][1] = fmaf(s4.x, sv[0].y, fmaf(s4.y, sv[1].y,
                       fmaf(s4.z, sv[2].y, fmaf(s4.w, sv[3].y, zs[r][1]))));
        }
    }

    const int mf = *maskFlag;
    const int2 md2 = *(const int2*)(wsMode + (b << 10) + tcol);
#pragma unroll
    for (int r = 0; r < 8; ++r) {
        const int s_r = sBase + r;
        const int row = rowBase + r;
        const float Hn = wsHn[row];
        const int mS = wsMode[row];
        int blk0, blk1;
        const size_t mb = (size_t)s_r * SEQ_ + tcol;
        if (mf == 1) {
            const unsigned char* m8 = (const unsigned char*)maskP;
            blk0 = m8[mb] != 0; blk1 = m8[mb + 1] != 0;
        } else if (mf == 2) {
            const float* mfl = (const float*)maskP;
            blk0 = mfl[mb] != 0.f; blk1 = mfl[mb + 1] != 0.f;
        } else {
            const int* m32 = (const int*)maskP;
            blk0 = m32[mb] != 0; blk1 = m32[mb + 1] != 0;
        }
        if (s_r == tcol) blk0 = 1;
        if (s_r == tcol + 1) blk1 = 1;
        const float zg0 = blk0 ? NEG_ : (ze[r][0] * Hn + 0.5f * zh[r][0]) * 5.0f;
        const float zg1 = blk1 ? NEG_ : (ze[r][1] * Hn + 0.5f * zh[r][1]) * 5.0f;
        const float zl0 = (!blk0 && md2.x == mS) ? zs[r][0] * 5.0f : (blk0 ? BLKNEG_ : 0.0f);
        const float zl1 = (!blk1 && md2.y == mS) ? zs[r][1] * 5.0f : (blk1 ? BLKNEG_ : 0.0f);
        *(float2*)(zgO + (size_t)row * SEQ_ + tcol) = make_float2(zg0, zg1);
        *(float2*)(zlO + (size_t)row * SEQ_ + tcol) = make_float2(zl0, zl1);
    }
}

// Kernel B: one wave per row -- sparsemax (support iteration) + sparse
// aggregation + static neighbor branch + fused epilogue.
__global__ __launch_bounds__(64) void route_kernel(
    const float* __restrict__ messages,
    const float* __restrict__ scn,
    const int* __restrict__ x_ids,
    const int* __restrict__ static_nb,
    const float* __restrict__ W_e1,
    const float* __restrict__ b_e1,
    const float* __restrict__ W_e2,
    const float* __restrict__ b_e2,
    const float* __restrict__ wsProbe,
    const float* __restrict__ wsGw,
    const float* __restrict__ zgA,
    const float* __restrict__ zlA,
    float* __restrict__ out)
{
    __shared__ int mlist[64];
    const int row = blockIdx.x;
    const int b = row >> 10, s_r = row & 1023;
    const int lane = threadIdx.x;
    const float* msgB = messages + (size_t)b * SEQ_ * D_;
    const float* scnB = scn + (size_t)b * SEQ_ * NS_;

    float zr[16];
    // ----- geo: load z (blocked layout: t = lane*16 + j) -----
    {
        const float4* zp = (const float4*)(zgA + (size_t)row * SEQ_ + (lane << 4));
#pragma unroll
        for (int q = 0; q < 4; ++q) {
            const float4 z4 = zp[q];
            zr[q * 4 + 0] = z4.x; zr[q * 4 + 1] = z4.y;
            zr[q * 4 + 2] = z4.z; zr[q * 4 + 3] = z4.w;
        }
    }
    const float tauG = sparsemaxTauWave(zr);
    float ax = 0.f, ay = 0.f, az = 0.f, aw = 0.f;
#pragma unroll
    for (int j = 0; j < 16; ++j) {
        const float wv = zr[j] - tauG;
        unsigned long long m = __ballot(wv > 0.f);
        while (m) {
            const int s0 = __ffsll(m) - 1; m &= m - 1;
            const float w0 = __shfl(wv, s0, 64);
            const float4 a4 = *(const float4*)(msgB + (size_t)((s0 << 4) + j) * D_ + (lane << 2));
            if (m) {
                const int s1 = __ffsll(m) - 1; m &= m - 1;
                const float w1 = __shfl(wv, s1, 64);
                const float4 b4 = *(const float4*)(msgB + (size_t)((s1 << 4) + j) * D_ + (lane << 2));
                ax = fmaf(w1, b4.x, ax); ay = fmaf(w1, b4.y, ay);
                az = fmaf(w1, b4.z, az); aw = fmaf(w1, b4.w, aw);
            }
            ax = fmaf(w0, a4.x, ax); ay = fmaf(w0, a4.y, ay);
            az = fmaf(w0, a4.z, az); aw = fmaf(w0, a4.w, aw);
        }
    }

    // ----- local: load zl, detect hasNb, fallback, sparsemax -----
    {
        const float4* zp = (const float4*)(zlA + (size_t)row * SEQ_ + (lane << 4));
#pragma unroll
        for (int q = 0; q < 4; ++q) {
            const float4 z4 = zp[q];
            zr[q * 4 + 0] = z4.x; zr[q * 4 + 1] = z4.y;
            zr[q * 4 + 2] = z4.z; zr[q * 4 + 3] = z4.w;
        }
    }
    int fl = 0;
#pragma unroll
    for (int j = 0; j < 16; ++j) fl |= (zr[j] != 0.0f && zr[j] > -40000.f);
    const int hasNb = __any(fl);
    if (!hasNb) {
#pragma unroll
        for (int j = 0; j < 16; ++j) {
            const int t = (lane << 4) + j;
            zr[j] = (zr[j] <= -40000.f) ? BLKNEG_ : -0.05f * fabsf((float)(s_r - t));
        }
    }
    const float tauL = sparsemaxTauWave(zr);
    float bx = 0.f, by = 0.f, bz = 0.f, bw = 0.f;
#pragma unroll
    for (int j = 0; j < 16; ++j) {
        const float wv = zr[j] - tauL;
        unsigned long long m = __ballot(wv > 0.f);
        while (m) {
            const int s0 = __ffsll(m) - 1; m &= m - 1;
            const float w0 = __shfl(wv, s0, 64);
            const float4 a4 = *(const float4*)(msgB + (size_t)((s0 << 4) + j) * D_ + (lane << 2));
            if (m) {
                const int s1 = __ffsll(m) - 1; m &= m - 1;
                const float w1 = __shfl(wv, s1, 64);
                const float4 b4 = *(const float4*)(msgB + (size_t)((s1 << 4) + j) * D_ + (lane << 2));
                bx = fmaf(w1, b4.x, bx); by = fmaf(w1, b4.y, by);
                bz = fmaf(w1, b4.z, bz); bw = fmaf(w1, b4.w, bw);
            }
            bx = fmaf(w0, a4.x, bx); by = fmaf(w0, a4.y, by);
            bz = fmaf(w0, a4.z, bz); bw = fmaf(w0, a4.w, bw);
        }
    }

    // ----- static neighbor-vocab branch -----
    const int q = x_ids[row];
    int nb[KNB_];
#pragma unroll
    for (int k = 0; k < KNB_; ++k) nb[k] = static_nb[(size_t)q * KNB_ + k];
    const float ss_l = scnB[(size_t)s_r * NS_ + lane];
    float simk[KNB_] = {};
    int cntk[KNB_] = {};
    int mcW = 0;
    const int* xb = x_ids + (b << 10);
    for (int pb = 0; pb <= s_r; pb += 64) {
        const int p = pb + lane;
        const int id = (p <= s_r) ? xb[p] : -1;
#pragma unroll
        for (int k = 0; k < KNB_; ++k) {
            unsigned long long mbit = __ballot(id == nb[k]);
            if (mbit) {
                cntk[k] += __popcll(mbit);
                while (mbit) {
                    const int src = __ffsll(mbit) - 1;
                    mbit &= mbit - 1;
                    const int pp = pb + src;
                    float pv = scnB[(size_t)pp * NS_ + lane] * ss_l;
                    pv = waveSum(pv);
                    simk[k] += pv;
                    if (mcW < 64) { if (lane == 0) mlist[mcW] = (pp << 3) | k; ++mcW; }
                }
            }
        }
    }
    // edge MLP: lane = k*8 + j computes one gelu term
    const int kk = lane >> 3, jjn = lane & 7;
    float sv = simk[0];
#pragma unroll
    for (int k = 1; k < KNB_; ++k) sv = (kk == k) ? simk[k] : sv;
    const float xx = sv * W_e1[jjn] + b_e1[jjn];
    float eo = 0.5f * xx * (1.f + erff(xx * 0.70710678118654752f)) * W_e2[jjn];
    eo += __shfl_xor(eo, 1, 64); eo += __shfl_xor(eo, 2, 64); eo += __shfl_xor(eo, 4, 64);
    eo += b_e2[0];
    float m2 = eo;
    m2 = fmaxf(m2, __shfl_xor(m2, 8, 64));
    m2 = fmaxf(m2, __shfl_xor(m2, 16, 64));
    m2 = fmaxf(m2, __shfl_xor(m2, 32, 64));
    const float exv = expf(eo - m2);
    float smv = exv;
    smv += __shfl_xor(smv, 8, 64); smv += __shfl_xor(smv, 16, 64); smv += __shfl_xor(smv, 32, 64);
    const float ewk = exv / smv;

    float cov = 0.f;
#pragma unroll
    for (int k = 0; k < KNB_; ++k) cov += fminf((float)cntk[k], 1.f);
    cov *= 0.125f;

    float cx = 0.f, cy = 0.f, cz = 0.f, cw = 0.f;
    const int nm = (mcW < 64) ? mcW : 64;
    for (int i2 = 0; i2 < nm; ++i2) {
        const int ee = mlist[i2];
        const int pp = ee >> 3, k2 = ee & 7;
        const float wgt = __shfl(ewk, k2 << 3, 64);
        const float4 m4 = *(const float4*)(msgB + (size_t)pp * D_ + (lane << 2));
        cx = fmaf(wgt, m4.x, cx); cy = fmaf(wgt, m4.y, cy);
        cz = fmaf(wgt, m4.z, cz); cw = fmaf(wgt, m4.w, cw);
    }

    // ----- gated fusion epilogue -----
    const float gw = wsGw[row];
    const float icov = 1.f - cov, igw = 1.f - gw;
    const float fx = gw * ax + igw * (cov * cx + icov * bx);
    const float fy = gw * ay + igw * (cov * cy + icov * by);
    const float fz = gw * az + igw * (cov * cz + icov * bz);
    const float fw = gw * aw + igw * (cov * cw + icov * bw);
    float ssq = fx * fx + fy * fy + fz * fz + fw * fw;
    ssq = waveSum(ssq);
    const float nrm = fmaxf(sqrtf(ssq), 1e-12f);
    const float4 pr = *(const float4*)(wsProbe + (size_t)row * D_ + (lane << 2));
    float dp = (fx * pr.x + fy * pr.y + fz * pr.z + fw * pr.w) / nrm;
    dp = waveSum(dp);
    const float rel = 1.f / (1.f + expf(-dp));
    *(float4*)(out + (size_t)row * D_ + (lane << 2)) =
        make_float4(fx * rel, fy * rel, fz * rel, fw * rel);
}

extern "C" void kernel_launch(void* const* d_in, const int* in_sizes, int n_in,
                              void* d_out, int out_size, void* d_ws, size_t ws_size,
                              hipStream_t stream) {
    const float* messages  = (const float*)d_in[0];
    const float* hidden    = (const float*)d_in[1];
    const int*   x_ids     = (const int*)d_in[2];
    const float* scn       = (const float*)d_in[3];
    const void*  mask      = d_in[4];
    const int*   static_nb = (const int*)d_in[5];
    const float* gvel      = (const float*)d_in[6];
    const float* ctx       = (const float*)d_in[7];
    const float* ent       = (const float*)d_in[8];
    const float* W_vel     = (const float*)d_in[9];
    const float* W_e1      = (const float*)d_in[10];
    const float* b_e1      = (const float*)d_in[11];
    const float* W_e2      = (const float*)d_in[12];
    const float* b_e2      = (const float*)d_in[13];
    const float* W_probe   = (const float*)d_in[14];
    const float* W_gate    = (const float*)d_in[15];
    const float* b_gate    = (const float*)d_in[16];
    float* out = (float*)d_out;
    (void)in_sizes; (void)n_in; (void)out_size; (void)ws_size;

    char* ws = (char*)d_ws;
    size_t o = 0;
    int* flag      = (int*)(ws + o);   o += 256;
    float* wsEnd   = (float*)(ws + o); o += (size_t)B_ * SEQ_ * NS_ * 4;
    float* wsHa    = (float*)(ws + o); o += (size_t)B_ * SEQ_ * D_ * 4;
    float* wsProbe = (float*)(ws + o); o += (size_t)B_ * SEQ_ * D_ * 4;
    int* wsMode    = (int*)(ws + o);   o += (size_t)B_ * SEQ_ * 4;
    float* wsHn    = (float*)(ws + o); o += (size_t)B_ * SEQ_ * 4;
    float* wsGw    = (float*)(ws + o); o += (size_t)B_ * SEQ_ * 4;
    float* msgT    = (float*)(ws + o); o += (size_t)B_ * D_ * SEQ_ * 4;
    float* scnT    = (float*)(ws + o); o += (size_t)B_ * NS_ * SEQ_ * 4;
    float* WpT     = (float*)(ws + o); o += (size_t)D_ * D_ * 4;
    float* WvT     = (float*)(ws + o); o += (size_t)D_ * NS_ * 4;
    float* zgW     = (float*)(ws + o); o += (size_t)B_ * SEQ_ * SEQ_ * 4;
    float* zlW     = (float*)(ws + o); o += (size_t)B_ * SEQ_ * SEQ_ * 4;

    transpose_all<<<dim3(1361), dim3(32, 8), 0, stream>>>(
        messages, scn, W_probe, W_vel, msgT, scnT, WpT, WvT,
        (const unsigned int*)mask, flag);
    prep4_kernel<<<dim3(B_ * SEQ_ / 4), dim3(256), 0, stream>>>(
        hidden, scn, gvel, ctx, ent, WpT, WvT, W_gate, b_gate,
        wsEnd, wsHa, wsProbe, wsMode, wsHn, wsGw);
    sims_kernel<<<dim3(512), dim3(512), 0, stream>>>(
        msgT, scnT, scn, wsHa, wsEnd, wsMode, wsHn, mask, flag, zgW, zlW);
    route_kernel<<<dim3(B_ * SEQ_), dim3(64), 0, stream>>>(
        messages, scn, x_ids, static_nb, W_e1, b_e1, W_e2, b_e2,
        wsProbe, wsGw, zgW, zlW, out);
}